// Round 12
// baseline (430.431 us; speedup 1.0000x reference)
//
#include <hip/hip_runtime.h>
#include <hip/hip_bf16.h>

#define NPTS 524288   // 64 * 8192
#define NBATCH 64
#define NSAMP 131072  // 4x-subsampled BN2/BN3 stats denominator

typedef __attribute__((ext_vector_type(8))) short bf16x8;
typedef __attribute__((ext_vector_type(4))) float f32x4;
typedef const float* __restrict__ fp;

__device__ __forceinline__ __hip_bfloat16 f2b(float v) { return __float2bfloat16(v); }
__device__ __forceinline__ unsigned bfbits(float v) {
    union { __hip_bfloat16 h; unsigned short s; } u; u.h = f2b(v); return (unsigned)u.s;
}
__device__ __forceinline__ unsigned pk2(float a, float b) {
    return bfbits(a) | (bfbits(b) << 16);
}
__device__ __forceinline__ float lo2f(unsigned u) { return __uint_as_float(u << 16); }
__device__ __forceinline__ float hi2f(unsigned u) { return __uint_as_float(u & 0xffff0000u); }

__device__ __forceinline__ unsigned fkey(float f) {
    unsigned u = __float_as_uint(f);
    return u ^ ((u & 0x80000000u) ? 0xFFFFFFFFu : 0x80000000u);
}
__device__ __forceinline__ float funkey(unsigned k) {
    unsigned u = (k & 0x80000000u) ? (k ^ 0x80000000u) : ~k;
    return __uint_as_float(u);
}

union U8 { bf16x8 v; __hip_bfloat16 e[8]; unsigned u[4]; };

static __device__ __forceinline__ f32x4 mfma16(bf16x8 a, bf16x8 b, f32x4 c) {
    return __builtin_amdgcn_mfma_f32_16x16x32_bf16(a, b, c, 0, 0, 0);
}

// ---------------- K1: fused W-convert (blocks >=1024) + pcd moments ---------
// W3b is SIGN-FOLDED: W3b[ch][k] = sign(g3[ch]) * W3[ch][k] -> max-only pool.
__launch_bounds__(256)
__global__ void k_setup(fp pcd, float* __restrict__ mom,
                        fp W2, fp W3, fp g3,
                        __hip_bfloat16* __restrict__ W2b,
                        __hip_bfloat16* __restrict__ W3b)
{
    if (blockIdx.x >= 1024) {   // prep branch: 160 blocks cover 8192+32768
        const int i = (blockIdx.x - 1024) * 256 + threadIdx.x;
        if (i < 8192) W2b[i] = f2b(W2[i]);
        const int j = i - 8192;
        if (j >= 0 && j < 32768) {
            const float s = (g3[j >> 7] < 0.f) ? -1.f : 1.f;
            W3b[j] = f2b(s * W3[j]);
        }
        return;
    }
    float s[9];
#pragma unroll
    for (int i = 0; i < 9; ++i) s[i] = 0.f;
    for (int p = blockIdx.x * 256 + threadIdx.x; p < NPTS; p += 262144) {
        const float x = pcd[3*p+0], y = pcd[3*p+1], z = pcd[3*p+2];
        s[0] += x; s[1] += y; s[2] += z;
        s[3] = fmaf(x, x, s[3]); s[4] = fmaf(x, y, s[4]); s[5] = fmaf(x, z, s[5]);
        s[6] = fmaf(y, y, s[6]); s[7] = fmaf(y, z, s[7]); s[8] = fmaf(z, z, s[8]);
    }
#pragma unroll
    for (int off = 1; off < 64; off <<= 1) {
#pragma unroll
        for (int i = 0; i < 9; ++i) s[i] += __shfl_xor(s[i], off);
    }
    __shared__ float red[4][9];
    const int lane = threadIdx.x & 63, wv = threadIdx.x >> 6;
    if (lane == 0) {
#pragma unroll
        for (int i = 0; i < 9; ++i) red[wv][i] = s[i];
    }
    __syncthreads();
    if (threadIdx.x < 9) {
        const int i = threadIdx.x;
        atomicAdd(&mom[i], red[0][i] + red[1][i] + red[2][i] + red[3][i]);
    }
}

// ---------------- K2: analytic BN1 folded straight into W1 ------------------
__global__ void k_fin1(const float* __restrict__ mom, fp W1, fp b1, fp g1, fp be1,
                       unsigned* __restrict__ W1p)
{
    const int c = threadIdx.x;  // 64 threads
    const float inv = 1.f / (float)NPTS;
    const float m0 = mom[0]*inv, m1 = mom[1]*inv, m2 = mom[2]*inv;
    const float c00 = mom[3]*inv - m0*m0, c01 = mom[4]*inv - m0*m1, c02 = mom[5]*inv - m0*m2;
    const float c11 = mom[6]*inv - m1*m1, c12 = mom[7]*inv - m1*m2, c22 = mom[8]*inv - m2*m2;
    const float w0 = W1[c*3+0], w1 = W1[c*3+1], w2 = W1[c*3+2];
    const float mu = w0*m0 + w1*m1 + w2*m2 + b1[c];
    float var = w0*w0*c00 + w1*w1*c11 + w2*w2*c22 + 2.f*(w0*w1*c01 + w0*w2*c02 + w1*w2*c12);
    var = fmaxf(var, 0.f);
    const float sc = g1[c] * rsqrtf(var + 1e-5f);
    const float sh = be1[c] - mu*sc;
    W1p[c*2+0] = pk2(w0*sc, w1*sc);
    W1p[c*2+1] = pk2(w2*sc, b1[c]*sc + sh);
}

// Per-lane VALU L1 -> L2 A-fragment in place; pairwise pack (2 live temps).
#define L1_DIRECT(a2f, px, py, pz)                                              \
    {                                                                           \
        _Pragma("unroll")                                                       \
        for (int ks = 0; ks < 2; ++ks) {                                        \
            _Pragma("unroll")                                                   \
            for (int t2 = 0; t2 < 4; ++t2) {                                    \
                const int t0 = ks*8 + 2*t2;                                     \
                float v0 = fmaf(px, lo2f(wA[t0]), hi2f(wB[t0]));                \
                v0 = fmaf(py, hi2f(wA[t0]), v0);                                \
                v0 = fmaf(pz, lo2f(wB[t0]), v0);                                \
                float v1 = fmaf(px, lo2f(wA[t0+1]), hi2f(wB[t0+1]));            \
                v1 = fmaf(py, hi2f(wA[t0+1]), v1);                              \
                v1 = fmaf(pz, lo2f(wB[t0+1]), v1);                              \
                a2f[ks].u[t2] = pk2(fmaxf(v0, 0.f), fmaxf(v1, 0.f));            \
            }                                                                   \
        }                                                                       \
    }

#define LOAD_W1()                                                               \
    unsigned wA[16], wB[16];                                                    \
    _Pragma("unroll")                                                           \
    for (int t = 0; t < 16; ++t) {                                              \
        const int ch = (t >> 3)*32 + q*8 + (t & 7);                             \
        wA[t] = W1p[ch*2]; wB[t] = W1p[ch*2+1];                                 \
    }

// ---------------- Pass 1: L1 + L2, y2 raw stats on a 1/4 SUBSAMPLE ----------
// 512 blocks x 256 thr; demand ~130 <= 168 budget -> no spill (r9-r11 verified).
__launch_bounds__(256, 3)
__global__ void k_pass1(fp pcd, const unsigned* __restrict__ W1p,
                        const __hip_bfloat16* __restrict__ W2b,
                        float* __restrict__ st2s, float* __restrict__ st2q)
{
    __shared__ float red[1024];
    const int tid = threadIdx.x, wv = tid >> 6, lane = tid & 63;
    const int m = lane & 15, q = lane >> 4;
    const int batch = blockIdx.x >> 3, sub = blockIdx.x & 7;

    LOAD_W1()
    bf16x8 wb2[8][2];
#pragma unroll
    for (int nt = 0; nt < 8; ++nt) {
#pragma unroll
        for (int kk = 0; kk < 2; ++kk)
            wb2[nt][kk] = *(const bf16x8*)(W2b + (nt*16+m)*64 + kk*32 + q*8);
    }

    float s_acc[8], q_acc[8];
#pragma unroll
    for (int nt = 0; nt < 8; ++nt) { s_acc[nt] = 0.f; q_acc[nt] = 0.f; }

#pragma unroll
    for (int it = 0; it < 4; ++it) {
        const int p0 = batch*8192 + sub*1024 + it*256 + wv*16;   // strided sample
        const float* pp = pcd + (size_t)(p0 + m) * 3;
        const float px = pp[0], py = pp[1], pz = pp[2];
        U8 a2f[2];
        L1_DIRECT(a2f, px, py, pz)
#pragma unroll
        for (int nt = 0; nt < 8; ++nt) {
            f32x4 c = mfma16(a2f[0].v, wb2[nt][0], (f32x4){0.f,0.f,0.f,0.f});
            c = mfma16(a2f[1].v, wb2[nt][1], c);
            s_acc[nt] += (c[0] + c[1]) + (c[2] + c[3]);
            q_acc[nt] = fmaf(c[0],c[0], fmaf(c[1],c[1], fmaf(c[2],c[2], fmaf(c[3],c[3], q_acc[nt]))));
        }
    }
#pragma unroll
    for (int nt = 0; nt < 8; ++nt) {
        s_acc[nt] += __shfl_xor(s_acc[nt], 16); q_acc[nt] += __shfl_xor(q_acc[nt], 16);
        s_acc[nt] += __shfl_xor(s_acc[nt], 32); q_acc[nt] += __shfl_xor(q_acc[nt], 32);
    }
    if (q == 0) {
#pragma unroll
        for (int nt = 0; nt < 8; ++nt) {
            red[wv*128 + nt*16 + m] = s_acc[nt];
            red[512 + wv*128 + nt*16 + m] = q_acc[nt];
        }
    }
    __syncthreads();
    if (tid < 128) {
        float s = 0.f, ss = 0.f;
#pragma unroll
        for (int w4 = 0; w4 < 4; ++w4) { s += red[w4*128 + tid]; ss += red[512 + w4*128 + tid]; }
        const int slot = blockIdx.x & 63;
        atomicAdd(&st2s[slot*128 + tid], s);
        atomicAdd(&st2q[slot*128 + tid], ss);
    }
}

// ---------------- K4: finalize BN2 + fold s2 into W2 (scaled copy) ----------
__global__ void k_fin2(const float* __restrict__ sum, const float* __restrict__ sq,
                       fp W2, fp g, fp be,
                       float* __restrict__ tOut, __hip_bfloat16* __restrict__ W2s)
{
    const int ch = threadIdx.x;  // 128
    float s = 0.f, ss = 0.f;
    for (int slot = 0; slot < 64; ++slot) { s += sum[slot*128 + ch]; ss += sq[slot*128 + ch]; }
    const float inv = 1.f / (float)NSAMP;
    const float mu = s * inv;
    const float var = fmaxf(ss * inv - mu*mu, 0.f);
    const float sc = g[ch] * rsqrtf(var + 1e-5f);
    tOut[ch] = be[ch] - mu*sc;
    for (int k = 0; k < 64; ++k) W2s[ch*64 + k] = f2b(sc * W2[ch*64 + k]);
}

// ---------------- Pass 2: half-tile x2 (34.8 KB) + W2 in LDS (18.4 KB) ------
// 53.25 KB -> 3 blocks/CU; post-folding register demand ~150 <= 168 budget of
// (256,3) -> no spill (the r9 config, now viable). BN3 stats on a 1/4
// subsample (half 0, ms<4); max-pool sees all points.
__launch_bounds__(256, 3)
__global__ void k_pass2(fp pcd, const unsigned* __restrict__ W1p,
                        const __hip_bfloat16* __restrict__ W2s,
                        const float* __restrict__ t2,
                        const __hip_bfloat16* __restrict__ W3b,
                        float* __restrict__ st3s, float* __restrict__ st3q,
                        unsigned* __restrict__ maxk)
{
    __shared__ alignas(16) __hip_bfloat16 x2s[128*136];   // 34816 B, stride 136
    __shared__ alignas(16) __hip_bfloat16 w2s[128*72];    // 18432 B, stride 72
    const int tid = threadIdx.x, wv = tid >> 6, lane = tid & 63;
    const int m = lane & 15, q = lane >> 4;
    const int batch = blockIdx.x >> 5, sub = blockIdx.x & 31;

    // stage scaled W2 -> LDS (128 rows x 64 cols)
    {
        const int row = tid >> 1, hf = tid & 1;
#pragma unroll
        for (int jj = 0; jj < 2; ++jj) {
            const bf16x8 wa = *(const bf16x8*)(W2s + row*64 + hf*32 + jj*16);
            const bf16x8 wb = *(const bf16x8*)(W2s + row*64 + hf*32 + jj*16 + 8);
            *(bf16x8*)&w2s[row*72 + hf*32 + jj*16]     = wa;
            *(bf16x8*)&w2s[row*72 + hf*32 + jj*16 + 8] = wb;
        }
    }

    LOAD_W1()
    float t2v[8];
#pragma unroll
    for (int nt = 0; nt < 8; ++nt) t2v[nt] = t2[nt*16+m];

    bf16x8 wb3[4][4];
#pragma unroll
    for (int nt = 0; nt < 4; ++nt) {
        const int ch3 = wv*64 + nt*16 + m;
#pragma unroll
        for (int ks = 0; ks < 4; ++ks)
            wb3[nt][ks] = *(const bf16x8*)(W3b + ch3*128 + ks*32 + q*8);
    }

    float s3[4], q3[4], mx3[4];
#pragma unroll
    for (int nt = 0; nt < 4; ++nt) { s3[nt]=0.f; q3[nt]=0.f; mx3[nt]=-3.4e38f; }

    __syncthreads();   // w2s staged

#pragma unroll
    for (int half = 0; half < 2; ++half) {
        if (half) __syncthreads();   // prev half's reads done before rewrite
        // ---- phase A: 2 front-end iterations -> x2 rows [0,128) ----
#pragma unroll
        for (int it = 0; it < 2; ++it) {
            const int p0 = batch*8192 + sub*256 + (half*2+it)*64 + wv*16;
            const float* pp = pcd + (size_t)(p0 + m) * 3;
            const float px = pp[0], py = pp[1], pz = pp[2];
            U8 a2f[2];
            L1_DIRECT(a2f, px, py, pz)
#pragma unroll
            for (int nt = 0; nt < 8; ++nt) {
                const bf16x8 wb20 = *(const bf16x8*)&w2s[(nt*16+m)*72 + 0  + q*8];
                const bf16x8 wb21 = *(const bf16x8*)&w2s[(nt*16+m)*72 + 32 + q*8];
                f32x4 c = mfma16(a2f[0].v, wb20, (f32x4){0.f,0.f,0.f,0.f});
                c = mfma16(a2f[1].v, wb21, c);
#pragma unroll
                for (int r = 0; r < 4; ++r) {
                    const float v = fmaxf(c[r] + t2v[nt], 0.f);   // s2 folded into W2
                    const unsigned own = bfbits(v);
                    const unsigned oth = (unsigned)__shfl_xor((int)own, 1);
                    if ((m & 1) == 0) {
                        const int row = it*64 + wv*16 + q*4 + r;
                        *(unsigned*)&x2s[row*136 + nt*16 + m] = own | (oth << 16);
                    }
                }
            }
        }
        __syncthreads();   // x2 half-tile complete
        // ---- phase B: L3 over 128 points x this wave's 64 channels ----
        for (int ms = 0; ms < 8; ++ms) {
            const int rowM = (ms*16 + m) * 136;
            bf16x8 a3[4];
#pragma unroll
            for (int ks = 0; ks < 4; ++ks)
                a3[ks] = *(const bf16x8*)&x2s[rowM + ks*32 + q*8];
            const bool dostat = (half == 0) && (ms < 4);
#pragma unroll
            for (int nt = 0; nt < 4; ++nt) {
                f32x4 c = mfma16(a3[0], wb3[nt][0], (f32x4){0.f,0.f,0.f,0.f});
                c = mfma16(a3[1], wb3[nt][1], c);
                c = mfma16(a3[2], wb3[nt][2], c);
                c = mfma16(a3[3], wb3[nt][3], c);
                mx3[nt] = fmaxf(fmaxf(c[0], c[1]), fmaxf(fmaxf(c[2], c[3]), mx3[nt]));
                if (dostat) {
                    s3[nt] += (c[0] + c[1]) + (c[2] + c[3]);
                    q3[nt] = fmaf(c[0],c[0], fmaf(c[1],c[1], fmaf(c[2],c[2], fmaf(c[3],c[3], q3[nt]))));
                }
            }
        }
    }
#pragma unroll
    for (int nt = 0; nt < 4; ++nt) {
        s3[nt] += __shfl_xor(s3[nt], 16);  q3[nt] += __shfl_xor(q3[nt], 16);
        mx3[nt] = fmaxf(mx3[nt], __shfl_xor(mx3[nt], 16));
        s3[nt] += __shfl_xor(s3[nt], 32);  q3[nt] += __shfl_xor(q3[nt], 32);
        mx3[nt] = fmaxf(mx3[nt], __shfl_xor(mx3[nt], 32));
    }
    if (q == 0) {
        const int slot = blockIdx.x & 63;
#pragma unroll
        for (int nt = 0; nt < 4; ++nt) {
            const int ch3 = wv*64 + nt*16 + m;
            atomicAdd(&st3s[slot*256 + ch3], s3[nt]);
            atomicAdd(&st3q[slot*256 + ch3], q3[nt]);
            atomicMax(&maxk[batch*256 + ch3], fkey(mx3[nt]));
        }
    }
}

// ---------------- K8: BN3-fold (primed, subsampled stats) + heads + QP ------
__launch_bounds__(128)
__global__ void k_head(const float* __restrict__ st3s, const float* __restrict__ st3q,
                       fp g3, fp be3, const unsigned* __restrict__ maxk,
                       fp Wfc, fp bfc, fp Wc1, fp bc1, fp Wc2, fp bc2,
                       fp Wp1, fp bp1, fp Wp2, fp bp2,
                       float* __restrict__ out)
{
    __shared__ float pf[256], ft[128], hcs[128], hps[64], ocs[48], nrm[36], hS[12], pp[8];
    const int bb = blockIdx.x, tid = threadIdx.x;
#pragma unroll
    for (int h = 0; h < 2; ++h) {
        const int ch = tid + h*128;
        float s = 0.f, ss = 0.f;
        for (int slot = 0; slot < 64; ++slot) { s += st3s[slot*256 + ch]; ss += st3q[slot*256 + ch]; }
        const float inv = 1.f / (float)NSAMP;
        const float mu = s * inv;    // primed mean (subsampled)
        const float var = fmaxf(ss * inv - mu*mu, 0.f);
        const float asc = fabsf(g3[ch]) * rsqrtf(var + 1e-5f);
        const float mx = funkey(maxk[bb*256 + ch]);
        pf[ch] = fmaxf(fmaf(asc, mx - mu, be3[ch]), 0.f);
    }
    __syncthreads();
    {
        float a = bfc[tid];
        const float* wr = Wfc + tid*256;
        for (int k = 0; k < 256; ++k) a = fmaf(pf[k], wr[k], a);
        ft[tid] = a;
    }
    __syncthreads();
    {
        float a = bc1[tid];
        const float* wr = Wc1 + tid*128;
        for (int k = 0; k < 128; ++k) a = fmaf(ft[k], wr[k], a);
        hcs[tid] = fmaxf(a, 0.f);
    }
    if (tid < 64) {
        float a = bp1[tid];
        const float* wr = Wp1 + tid*128;
        for (int k = 0; k < 128; ++k) a = fmaf(ft[k], wr[k], a);
        hps[tid] = fmaxf(a, 0.f);
    }
    __syncthreads();
    if (tid < 48) {
        float a = bc2[tid];
        const float* wr = Wc2 + tid*128;
        for (int k = 0; k < 128; ++k) a = fmaf(hcs[k], wr[k], a);
        ocs[tid] = a;
    }
    if (tid < 7) {
        float a = bp2[tid];
        const float* wr = Wp2 + tid*64;
        for (int k = 0; k < 64; ++k) a = fmaf(hps[k], wr[k], a);
        const float sc = (tid < 3) ? 0.1f : ((tid < 6) ? 1.57f : 0.05f);
        pp[tid] = tanhf(a) * sc;
    }
    __syncthreads();
    if (tid < 12) {
        float nx = ocs[tid*4+0], ny = ocs[tid*4+1], nz = ocs[tid*4+2];
        const float nn = fmaxf(sqrtf(nx*nx + ny*ny + nz*nz), 1e-12f);
        const float inv = 1.f / nn;
        nx *= inv; ny *= inv; nz *= inv;
        nrm[tid*3+0] = nx; nrm[tid*3+1] = ny; nrm[tid*3+2] = nz;
        const float xx = ocs[tid*4+3];
        hS[tid] = ((xx > 20.f) ? xx : log1pf(expf(xx))) + 0.005f;
    }
    __syncthreads();

    // QP via rank-3 structure: M = N N^T + eps*I  ->  grad = N(N^T lam) + eps*lam - q.
    // Each 16-lane group solves the full 12-dim QP; 3-value xor-tree reduction
    // replaces the 12-readlane broadcast (shorter dep chain).
    const int l15 = tid & 15;
    const int c = (l15 < 12) ? l15 : 11;
    const float mk = (l15 < 12) ? 1.f : 0.f;
    const float n0 = nrm[c*3+0], n1 = nrm[c*3+1], n2 = nrm[c*3+2];
    const float n0m = n0*mk, n1m = n1*mk, n2m = n2*mk;
    float trace = 0.f;
#pragma unroll
    for (int d = 0; d < 12; ++d)
        trace += nrm[d*3+0]*nrm[d*3+0] + nrm[d*3+1]*nrm[d*3+1] + nrm[d*3+2]*nrm[d*3+2];
    const float alpha = 1.f / (trace + 12.f*5e-4f);
    const float qc = n0*pp[0] + n1*pp[1] + n2*pp[2] - hS[c];
    float lam = 0.f;
    for (int it = 0; it < 500; ++it) {
        float wx = lam*n0m, wy = lam*n1m, wz = lam*n2m;
#pragma unroll
        for (int off = 1; off < 16; off <<= 1) {
            wx += __shfl_xor(wx, off);
            wy += __shfl_xor(wy, off);
            wz += __shfl_xor(wz, off);
        }
        const float grad = fmaf(n0, wx, fmaf(n1, wy, fmaf(n2, wz, fmaf(5e-4f, lam, -qc))));
        lam = fmaxf(fmaf(-alpha, grad, lam), 0.f);
    }
    float v0 = lam*n0m, v1 = lam*n1m, v2 = lam*n2m;
#pragma unroll
    for (int off = 1; off < 16; off <<= 1) {
        v0 += __shfl_xor(v0, off);
        v1 += __shfl_xor(v1, off);
        v2 += __shfl_xor(v2, off);
    }
    if (tid < 7) {
        float z;
        if (tid == 0) z = pp[0] - v0;
        else if (tid == 1) z = pp[1] - v1;
        else if (tid == 2) z = pp[2] - v2;
        else z = pp[tid];
        out[bb*7 + tid] = z;
    }
    if (tid < 36) out[448 + bb*36 + tid] = nrm[tid];
    if (tid < 12) out[2752 + bb*12 + tid] = hS[tid];
    if (tid < 7)  out[3520 + bb*7 + tid] = pp[tid];
}

// ---------------- host ------------------------------------------------------
extern "C" void kernel_launch(void* const* d_in, const int* in_sizes, int n_in,
                              void* d_out, int out_size, void* d_ws, size_t ws_size,
                              hipStream_t stream) {
    fp pcd = (fp)d_in[0];
    fp W1 = (fp)d_in[1],  b1 = (fp)d_in[2],  g1 = (fp)d_in[3],  be1 = (fp)d_in[4];
    fp W2 = (fp)d_in[5],  g2 = (fp)d_in[7],  be2 = (fp)d_in[8];
    fp W3 = (fp)d_in[9],  g3 = (fp)d_in[11], be3 = (fp)d_in[12];
    fp Wfc = (fp)d_in[13], bfc = (fp)d_in[14];
    fp Wc1 = (fp)d_in[15], bc1 = (fp)d_in[16];
    fp Wc2 = (fp)d_in[17], bc2 = (fp)d_in[18];
    fp Wp1 = (fp)d_in[19], bp1 = (fp)d_in[20];
    fp Wp2 = (fp)d_in[21], bp2 = (fp)d_in[22];
    // b2 (d_in[6]) / b3 (d_in[10]) cancel analytically in BN

    float* ws = (float*)d_ws;
    float* mom  = ws + 0;           // 16
    float* t2   = ws + 272;         // 128
    float* st2s = ws + 400;         // 64*128 = 8192
    float* st2q = ws + 8592;        // 8192
    float* st3s = ws + 16784;       // 64*256 = 16384
    float* st3q = ws + 33168;       // 16384
    unsigned* maxk = (unsigned*)(ws + 49552);   // 16384 (0-init = fkey(-inf))
    __hip_bfloat16* W2b = (__hip_bfloat16*)(ws + 82320);   // 8192 bf16 (raw)
    __hip_bfloat16* W3b = (__hip_bfloat16*)(ws + 86416);   // 32768 bf16 (sign-folded)
    unsigned* W1p = (unsigned*)(ws + 102800);              // 128 uint
    __hip_bfloat16* W2s = (__hip_bfloat16*)(ws + 102928);  // 8192 bf16 (s2-scaled)
    if (ws_size < (size_t)107024 * 4) return;

    hipMemsetAsync(d_ws, 0, (size_t)65936 * 4, stream);   // mom..maxk

    k_setup<<<1184, 256, 0, stream>>>(pcd, mom, W2, W3, g3, W2b, W3b);
    k_fin1<<<1, 64, 0, stream>>>(mom, W1, b1, g1, be1, W1p);
    k_pass1<<<512, 256, 0, stream>>>(pcd, W1p, W2b, st2s, st2q);
    k_fin2<<<1, 128, 0, stream>>>(st2s, st2q, W2, g2, be2, t2, W2s);
    k_pass2<<<2048, 256, 0, stream>>>(pcd, W1p, W2s, t2, W3b,
                                      st3s, st3q, maxk);
    k_head<<<64, 128, 0, stream>>>(st3s, st3q, g3, be3, maxk,
                                   Wfc, bfc, Wc1, bc1, Wc2, bc2,
                                   Wp1, bp1, Wp2, bp2, (float*)d_out);
}

// Round 13
// 312.239 us; speedup vs baseline: 1.3785x; 1.3785x over previous
//
#include <hip/hip_runtime.h>
#include <hip/hip_bf16.h>

#define NPTS 524288   // 64 * 8192
#define NBATCH 64
#define NSAMP 131072  // 4x-subsampled BN2/BN3 stats denominator

typedef __attribute__((ext_vector_type(8))) short bf16x8;
typedef __attribute__((ext_vector_type(4))) float f32x4;
typedef const float* __restrict__ fp;

__device__ __forceinline__ __hip_bfloat16 f2b(float v) { return __float2bfloat16(v); }
__device__ __forceinline__ unsigned bfbits(float v) {
    union { __hip_bfloat16 h; unsigned short s; } u; u.h = f2b(v); return (unsigned)u.s;
}
__device__ __forceinline__ unsigned pk2(float a, float b) {
    return bfbits(a) | (bfbits(b) << 16);
}
__device__ __forceinline__ float lo2f(unsigned u) { return __uint_as_float(u << 16); }
__device__ __forceinline__ float hi2f(unsigned u) { return __uint_as_float(u & 0xffff0000u); }

__device__ __forceinline__ unsigned fkey(float f) {
    unsigned u = __float_as_uint(f);
    return u ^ ((u & 0x80000000u) ? 0xFFFFFFFFu : 0x80000000u);
}
__device__ __forceinline__ float funkey(unsigned k) {
    unsigned u = (k & 0x80000000u) ? (k ^ 0x80000000u) : ~k;
    return __uint_as_float(u);
}

union U8 { bf16x8 v; __hip_bfloat16 e[8]; unsigned u[4]; };

static __device__ __forceinline__ f32x4 mfma16(bf16x8 a, bf16x8 b, f32x4 c) {
    return __builtin_amdgcn_mfma_f32_16x16x32_bf16(a, b, c, 0, 0, 0);
}

// ---------------- K1: fused W-convert (blocks >=1024) + pcd moments ---------
// W3b is SIGN-FOLDED: W3b[ch][k] = sign(g3[ch]) * W3[ch][k] -> max-only pool.
__launch_bounds__(256)
__global__ void k_setup(fp pcd, float* __restrict__ mom,
                        fp W2, fp W3, fp g3,
                        __hip_bfloat16* __restrict__ W2b,
                        __hip_bfloat16* __restrict__ W3b)
{
    if (blockIdx.x >= 1024) {   // prep branch: 160 blocks cover 8192+32768
        const int i = (blockIdx.x - 1024) * 256 + threadIdx.x;
        if (i < 8192) W2b[i] = f2b(W2[i]);
        const int j = i - 8192;
        if (j >= 0 && j < 32768) {
            const float s = (g3[j >> 7] < 0.f) ? -1.f : 1.f;
            W3b[j] = f2b(s * W3[j]);
        }
        return;
    }
    float s[9];
#pragma unroll
    for (int i = 0; i < 9; ++i) s[i] = 0.f;
    for (int p = blockIdx.x * 256 + threadIdx.x; p < NPTS; p += 262144) {
        const float x = pcd[3*p+0], y = pcd[3*p+1], z = pcd[3*p+2];
        s[0] += x; s[1] += y; s[2] += z;
        s[3] = fmaf(x, x, s[3]); s[4] = fmaf(x, y, s[4]); s[5] = fmaf(x, z, s[5]);
        s[6] = fmaf(y, y, s[6]); s[7] = fmaf(y, z, s[7]); s[8] = fmaf(z, z, s[8]);
    }
#pragma unroll
    for (int off = 1; off < 64; off <<= 1) {
#pragma unroll
        for (int i = 0; i < 9; ++i) s[i] += __shfl_xor(s[i], off);
    }
    __shared__ float red[4][9];
    const int lane = threadIdx.x & 63, wv = threadIdx.x >> 6;
    if (lane == 0) {
#pragma unroll
        for (int i = 0; i < 9; ++i) red[wv][i] = s[i];
    }
    __syncthreads();
    if (threadIdx.x < 9) {
        const int i = threadIdx.x;
        atomicAdd(&mom[i], red[0][i] + red[1][i] + red[2][i] + red[3][i]);
    }
}

// ---------------- K2: analytic BN1 folded straight into W1 ------------------
__global__ void k_fin1(const float* __restrict__ mom, fp W1, fp b1, fp g1, fp be1,
                       unsigned* __restrict__ W1p)
{
    const int c = threadIdx.x;  // 64 threads
    const float inv = 1.f / (float)NPTS;
    const float m0 = mom[0]*inv, m1 = mom[1]*inv, m2 = mom[2]*inv;
    const float c00 = mom[3]*inv - m0*m0, c01 = mom[4]*inv - m0*m1, c02 = mom[5]*inv - m0*m2;
    const float c11 = mom[6]*inv - m1*m1, c12 = mom[7]*inv - m1*m2, c22 = mom[8]*inv - m2*m2;
    const float w0 = W1[c*3+0], w1 = W1[c*3+1], w2 = W1[c*3+2];
    const float mu = w0*m0 + w1*m1 + w2*m2 + b1[c];
    float var = w0*w0*c00 + w1*w1*c11 + w2*w2*c22 + 2.f*(w0*w1*c01 + w0*w2*c02 + w1*w2*c12);
    var = fmaxf(var, 0.f);
    const float sc = g1[c] * rsqrtf(var + 1e-5f);
    const float sh = be1[c] - mu*sc;
    W1p[c*2+0] = pk2(w0*sc, w1*sc);
    W1p[c*2+1] = pk2(w2*sc, b1[c]*sc + sh);
}

// Per-lane VALU L1 -> L2 A-fragment in place; pairwise pack (2 live temps).
#define L1_DIRECT(a2f, px, py, pz)                                              \
    {                                                                           \
        _Pragma("unroll")                                                       \
        for (int ks = 0; ks < 2; ++ks) {                                        \
            _Pragma("unroll")                                                   \
            for (int t2 = 0; t2 < 4; ++t2) {                                    \
                const int t0 = ks*8 + 2*t2;                                     \
                float v0 = fmaf(px, lo2f(wA[t0]), hi2f(wB[t0]));                \
                v0 = fmaf(py, hi2f(wA[t0]), v0);                                \
                v0 = fmaf(pz, lo2f(wB[t0]), v0);                                \
                float v1 = fmaf(px, lo2f(wA[t0+1]), hi2f(wB[t0+1]));            \
                v1 = fmaf(py, hi2f(wA[t0+1]), v1);                              \
                v1 = fmaf(pz, lo2f(wB[t0+1]), v1);                              \
                a2f[ks].u[t2] = pk2(fmaxf(v0, 0.f), fmaxf(v1, 0.f));            \
            }                                                                   \
        }                                                                       \
    }

#define LOAD_W1()                                                               \
    unsigned wA[16], wB[16];                                                    \
    _Pragma("unroll")                                                           \
    for (int t = 0; t < 16; ++t) {                                              \
        const int ch = (t >> 3)*32 + q*8 + (t & 7);                             \
        wA[t] = W1p[ch*2]; wB[t] = W1p[ch*2+1];                                 \
    }

// ---------------- Pass 1: L1 + L2, y2 raw stats on a 1/4 SUBSAMPLE ----------
// 512 blocks x 256 thr; demand ~130 <= 168 budget -> no spill (r9-r11 verified).
__launch_bounds__(256, 3)
__global__ void k_pass1(fp pcd, const unsigned* __restrict__ W1p,
                        const __hip_bfloat16* __restrict__ W2b,
                        float* __restrict__ st2s, float* __restrict__ st2q)
{
    __shared__ float red[1024];
    const int tid = threadIdx.x, wv = tid >> 6, lane = tid & 63;
    const int m = lane & 15, q = lane >> 4;
    const int batch = blockIdx.x >> 3, sub = blockIdx.x & 7;

    LOAD_W1()
    bf16x8 wb2[8][2];
#pragma unroll
    for (int nt = 0; nt < 8; ++nt) {
#pragma unroll
        for (int kk = 0; kk < 2; ++kk)
            wb2[nt][kk] = *(const bf16x8*)(W2b + (nt*16+m)*64 + kk*32 + q*8);
    }

    float s_acc[8], q_acc[8];
#pragma unroll
    for (int nt = 0; nt < 8; ++nt) { s_acc[nt] = 0.f; q_acc[nt] = 0.f; }

#pragma unroll
    for (int it = 0; it < 4; ++it) {
        const int p0 = batch*8192 + sub*1024 + it*256 + wv*16;   // strided sample
        const float* pp = pcd + (size_t)(p0 + m) * 3;
        const float px = pp[0], py = pp[1], pz = pp[2];
        U8 a2f[2];
        L1_DIRECT(a2f, px, py, pz)
#pragma unroll
        for (int nt = 0; nt < 8; ++nt) {
            f32x4 c = mfma16(a2f[0].v, wb2[nt][0], (f32x4){0.f,0.f,0.f,0.f});
            c = mfma16(a2f[1].v, wb2[nt][1], c);
            s_acc[nt] += (c[0] + c[1]) + (c[2] + c[3]);
            q_acc[nt] = fmaf(c[0],c[0], fmaf(c[1],c[1], fmaf(c[2],c[2], fmaf(c[3],c[3], q_acc[nt]))));
        }
    }
#pragma unroll
    for (int nt = 0; nt < 8; ++nt) {
        s_acc[nt] += __shfl_xor(s_acc[nt], 16); q_acc[nt] += __shfl_xor(q_acc[nt], 16);
        s_acc[nt] += __shfl_xor(s_acc[nt], 32); q_acc[nt] += __shfl_xor(q_acc[nt], 32);
    }
    if (q == 0) {
#pragma unroll
        for (int nt = 0; nt < 8; ++nt) {
            red[wv*128 + nt*16 + m] = s_acc[nt];
            red[512 + wv*128 + nt*16 + m] = q_acc[nt];
        }
    }
    __syncthreads();
    if (tid < 128) {
        float s = 0.f, ss = 0.f;
#pragma unroll
        for (int w4 = 0; w4 < 4; ++w4) { s += red[w4*128 + tid]; ss += red[512 + w4*128 + tid]; }
        const int slot = blockIdx.x & 63;
        atomicAdd(&st2s[slot*128 + tid], s);
        atomicAdd(&st2q[slot*128 + tid], ss);
    }
}

// ---------------- K4: finalize BN2 + fold s2 into W2 (scaled copy) ----------
__global__ void k_fin2(const float* __restrict__ sum, const float* __restrict__ sq,
                       fp W2, fp g, fp be,
                       float* __restrict__ tOut, __hip_bfloat16* __restrict__ W2s)
{
    const int ch = threadIdx.x;  // 128
    float s = 0.f, ss = 0.f;
    for (int slot = 0; slot < 64; ++slot) { s += sum[slot*128 + ch]; ss += sq[slot*128 + ch]; }
    const float inv = 1.f / (float)NSAMP;
    const float mu = s * inv;
    const float var = fmaxf(ss * inv - mu*mu, 0.f);
    const float sc = g[ch] * rsqrtf(var + 1e-5f);
    tOut[ch] = be[ch] - mu*sc;
    for (int k = 0; k < 64; ++k) W2s[ch*64 + k] = f2b(sc * W2[ch*64 + k]);
}

// ---------------- Pass 2: round-11 structure (measured optimum) -------------
// Single 256-pt x2s tile (69.6 KB, 1 barrier), wb2 + wb3 register-stationary.
// launch_bounds(256,2): budget 256 >= demand ~180 -> no spill, no balloon.
// (r8: budget128=spill; r9/r12: budget168=spill; r10: unbounded=1 wave/SIMD.)
// BN3 stats on the ms<4 quarter-subsample; max-pool sees all points.
__launch_bounds__(256, 2)
__global__ void k_pass2(fp pcd, const unsigned* __restrict__ W1p,
                        const __hip_bfloat16* __restrict__ W2s,
                        const float* __restrict__ t2,
                        const __hip_bfloat16* __restrict__ W3b,
                        float* __restrict__ st3s, float* __restrict__ st3q,
                        unsigned* __restrict__ maxk)
{
    __shared__ alignas(16) __hip_bfloat16 x2s[256*136];   // 69.6 KB, stride 136
    const int tid = threadIdx.x, wv = tid >> 6, lane = tid & 63;
    const int m = lane & 15, q = lane >> 4;
    const int batch = blockIdx.x >> 5, sub = blockIdx.x & 31;

    LOAD_W1()
    bf16x8 wb2[8][2];
#pragma unroll
    for (int nt = 0; nt < 8; ++nt) {
#pragma unroll
        for (int kk = 0; kk < 2; ++kk)
            wb2[nt][kk] = *(const bf16x8*)(W2s + (nt*16+m)*64 + kk*32 + q*8);
    }
    float t2v[8];
#pragma unroll
    for (int nt = 0; nt < 8; ++nt) t2v[nt] = t2[nt*16+m];

    bf16x8 wb3[4][4];
#pragma unroll
    for (int nt = 0; nt < 4; ++nt) {
        const int ch3 = wv*64 + nt*16 + m;
#pragma unroll
        for (int ks = 0; ks < 4; ++ks)
            wb3[nt][ks] = *(const bf16x8*)(W3b + ch3*128 + ks*32 + q*8);
    }

    // ---- phase A: 4 independent front-end iterations, no barriers ----
#pragma unroll
    for (int it = 0; it < 4; ++it) {
        const int p0 = batch*8192 + sub*256 + it*64 + wv*16;
        const float* pp = pcd + (size_t)(p0 + m) * 3;
        const float px = pp[0], py = pp[1], pz = pp[2];
        U8 a2f[2];
        L1_DIRECT(a2f, px, py, pz)
#pragma unroll
        for (int nt = 0; nt < 8; ++nt) {
            f32x4 c = mfma16(a2f[0].v, wb2[nt][0], (f32x4){0.f,0.f,0.f,0.f});
            c = mfma16(a2f[1].v, wb2[nt][1], c);
#pragma unroll
            for (int r = 0; r < 4; ++r) {
                const float v = fmaxf(c[r] + t2v[nt], 0.f);   // s2 folded into W2
                const unsigned own = bfbits(v);
                const unsigned oth = (unsigned)__shfl_xor((int)own, 1);
                if ((m & 1) == 0) {
                    const int row = it*64 + wv*16 + q*4 + r;
                    *(unsigned*)&x2s[row*136 + nt*16 + m] = own | (oth << 16);
                }
            }
        }
    }
    __syncthreads();   // the ONLY barrier: all 256 x2 rows complete

    // ---- phase B: L3 (sign-folded) over 256 points x 64 channels/wave ----
    float s3[4], q3[4], mx3[4];
#pragma unroll
    for (int nt = 0; nt < 4; ++nt) { s3[nt]=0.f; q3[nt]=0.f; mx3[nt]=-3.4e38f; }

    for (int ms = 0; ms < 16; ++ms) {
        const int rowM = (ms*16 + m) * 136;
        bf16x8 a3[4];
#pragma unroll
        for (int ks = 0; ks < 4; ++ks)
            a3[ks] = *(const bf16x8*)&x2s[rowM + ks*32 + q*8];
        const bool dostat = (ms < 4);   // 1/4 stat subsample; max sees all
#pragma unroll
        for (int nt = 0; nt < 4; ++nt) {
            f32x4 c = mfma16(a3[0], wb3[nt][0], (f32x4){0.f,0.f,0.f,0.f});
            c = mfma16(a3[1], wb3[nt][1], c);
            c = mfma16(a3[2], wb3[nt][2], c);
            c = mfma16(a3[3], wb3[nt][3], c);
            mx3[nt] = fmaxf(fmaxf(c[0], c[1]), fmaxf(fmaxf(c[2], c[3]), mx3[nt]));
            if (dostat) {
                s3[nt] += (c[0] + c[1]) + (c[2] + c[3]);
                q3[nt] = fmaf(c[0],c[0], fmaf(c[1],c[1], fmaf(c[2],c[2], fmaf(c[3],c[3], q3[nt]))));
            }
        }
    }
#pragma unroll
    for (int nt = 0; nt < 4; ++nt) {
        s3[nt] += __shfl_xor(s3[nt], 16);  q3[nt] += __shfl_xor(q3[nt], 16);
        mx3[nt] = fmaxf(mx3[nt], __shfl_xor(mx3[nt], 16));
        s3[nt] += __shfl_xor(s3[nt], 32);  q3[nt] += __shfl_xor(q3[nt], 32);
        mx3[nt] = fmaxf(mx3[nt], __shfl_xor(mx3[nt], 32));
    }
    if (q == 0) {
        const int slot = blockIdx.x & 63;
#pragma unroll
        for (int nt = 0; nt < 4; ++nt) {
            const int ch3 = wv*64 + nt*16 + m;
            atomicAdd(&st3s[slot*256 + ch3], s3[nt]);
            atomicAdd(&st3q[slot*256 + ch3], q3[nt]);
            atomicMax(&maxk[batch*256 + ch3], fkey(mx3[nt]));
        }
    }
}

// ---------------- K8: BN3-fold (primed, subsampled stats) + heads + QP ------
__launch_bounds__(128)
__global__ void k_head(const float* __restrict__ st3s, const float* __restrict__ st3q,
                       fp g3, fp be3, const unsigned* __restrict__ maxk,
                       fp Wfc, fp bfc, fp Wc1, fp bc1, fp Wc2, fp bc2,
                       fp Wp1, fp bp1, fp Wp2, fp bp2,
                       float* __restrict__ out)
{
    __shared__ float pf[256], ft[128], hcs[128], hps[64], ocs[48], nrm[36], hS[12], pp[8];
    const int bb = blockIdx.x, tid = threadIdx.x;
#pragma unroll
    for (int h = 0; h < 2; ++h) {
        const int ch = tid + h*128;
        float s = 0.f, ss = 0.f;
        for (int slot = 0; slot < 64; ++slot) { s += st3s[slot*256 + ch]; ss += st3q[slot*256 + ch]; }
        const float inv = 1.f / (float)NSAMP;
        const float mu = s * inv;    // primed mean (subsampled)
        const float var = fmaxf(ss * inv - mu*mu, 0.f);
        const float asc = fabsf(g3[ch]) * rsqrtf(var + 1e-5f);
        const float mx = funkey(maxk[bb*256 + ch]);
        pf[ch] = fmaxf(fmaf(asc, mx - mu, be3[ch]), 0.f);
    }
    __syncthreads();
    {
        float a = bfc[tid];
        const float* wr = Wfc + tid*256;
        for (int k = 0; k < 256; ++k) a = fmaf(pf[k], wr[k], a);
        ft[tid] = a;
    }
    __syncthreads();
    {
        float a = bc1[tid];
        const float* wr = Wc1 + tid*128;
        for (int k = 0; k < 128; ++k) a = fmaf(ft[k], wr[k], a);
        hcs[tid] = fmaxf(a, 0.f);
    }
    if (tid < 64) {
        float a = bp1[tid];
        const float* wr = Wp1 + tid*128;
        for (int k = 0; k < 128; ++k) a = fmaf(ft[k], wr[k], a);
        hps[tid] = fmaxf(a, 0.f);
    }
    __syncthreads();
    if (tid < 48) {
        float a = bc2[tid];
        const float* wr = Wc2 + tid*128;
        for (int k = 0; k < 128; ++k) a = fmaf(hcs[k], wr[k], a);
        ocs[tid] = a;
    }
    if (tid < 7) {
        float a = bp2[tid];
        const float* wr = Wp2 + tid*64;
        for (int k = 0; k < 64; ++k) a = fmaf(hps[k], wr[k], a);
        const float sc = (tid < 3) ? 0.1f : ((tid < 6) ? 1.57f : 0.05f);
        pp[tid] = tanhf(a) * sc;
    }
    __syncthreads();
    if (tid < 12) {
        float nx = ocs[tid*4+0], ny = ocs[tid*4+1], nz = ocs[tid*4+2];
        const float nn = fmaxf(sqrtf(nx*nx + ny*ny + nz*nz), 1e-12f);
        const float inv = 1.f / nn;
        nx *= inv; ny *= inv; nz *= inv;
        nrm[tid*3+0] = nx; nrm[tid*3+1] = ny; nrm[tid*3+2] = nz;
        const float xx = ocs[tid*4+3];
        hS[tid] = ((xx > 20.f) ? xx : log1pf(expf(xx))) + 0.005f;
    }
    __syncthreads();

    // QP via rank-3 structure: grad = N(N^T lam) + eps*lam - q (xor-tree).
    const int l15 = tid & 15;
    const int c = (l15 < 12) ? l15 : 11;
    const float mk = (l15 < 12) ? 1.f : 0.f;
    const float n0 = nrm[c*3+0], n1 = nrm[c*3+1], n2 = nrm[c*3+2];
    const float n0m = n0*mk, n1m = n1*mk, n2m = n2*mk;
    float trace = 0.f;
#pragma unroll
    for (int d = 0; d < 12; ++d)
        trace += nrm[d*3+0]*nrm[d*3+0] + nrm[d*3+1]*nrm[d*3+1] + nrm[d*3+2]*nrm[d*3+2];
    const float alpha = 1.f / (trace + 12.f*5e-4f);
    const float qc = n0*pp[0] + n1*pp[1] + n2*pp[2] - hS[c];
    float lam = 0.f;
    for (int it = 0; it < 500; ++it) {
        float wx = lam*n0m, wy = lam*n1m, wz = lam*n2m;
#pragma unroll
        for (int off = 1; off < 16; off <<= 1) {
            wx += __shfl_xor(wx, off);
            wy += __shfl_xor(wy, off);
            wz += __shfl_xor(wz, off);
        }
        const float grad = fmaf(n0, wx, fmaf(n1, wy, fmaf(n2, wz, fmaf(5e-4f, lam, -qc))));
        lam = fmaxf(fmaf(-alpha, grad, lam), 0.f);
    }
    float v0 = lam*n0m, v1 = lam*n1m, v2 = lam*n2m;
#pragma unroll
    for (int off = 1; off < 16; off <<= 1) {
        v0 += __shfl_xor(v0, off);
        v1 += __shfl_xor(v1, off);
        v2 += __shfl_xor(v2, off);
    }
    if (tid < 7) {
        float z;
        if (tid == 0) z = pp[0] - v0;
        else if (tid == 1) z = pp[1] - v1;
        else if (tid == 2) z = pp[2] - v2;
        else z = pp[tid];
        out[bb*7 + tid] = z;
    }
    if (tid < 36) out[448 + bb*36 + tid] = nrm[tid];
    if (tid < 12) out[2752 + bb*12 + tid] = hS[tid];
    if (tid < 7)  out[3520 + bb*7 + tid] = pp[tid];
}

// ---------------- host ------------------------------------------------------
extern "C" void kernel_launch(void* const* d_in, const int* in_sizes, int n_in,
                              void* d_out, int out_size, void* d_ws, size_t ws_size,
                              hipStream_t stream) {
    fp pcd = (fp)d_in[0];
    fp W1 = (fp)d_in[1],  b1 = (fp)d_in[2],  g1 = (fp)d_in[3],  be1 = (fp)d_in[4];
    fp W2 = (fp)d_in[5],  g2 = (fp)d_in[7],  be2 = (fp)d_in[8];
    fp W3 = (fp)d_in[9],  g3 = (fp)d_in[11], be3 = (fp)d_in[12];
    fp Wfc = (fp)d_in[13], bfc = (fp)d_in[14];
    fp Wc1 = (fp)d_in[15], bc1 = (fp)d_in[16];
    fp Wc2 = (fp)d_in[17], bc2 = (fp)d_in[18];
    fp Wp1 = (fp)d_in[19], bp1 = (fp)d_in[20];
    fp Wp2 = (fp)d_in[21], bp2 = (fp)d_in[22];
    // b2 (d_in[6]) / b3 (d_in[10]) cancel analytically in BN

    float* ws = (float*)d_ws;
    float* mom  = ws + 0;           // 16
    float* t2   = ws + 272;         // 128
    float* st2s = ws + 400;         // 64*128 = 8192
    float* st2q = ws + 8592;        // 8192
    float* st3s = ws + 16784;       // 64*256 = 16384
    float* st3q = ws + 33168;       // 16384
    unsigned* maxk = (unsigned*)(ws + 49552);   // 16384 (0-init = fkey(-inf))
    __hip_bfloat16* W2b = (__hip_bfloat16*)(ws + 82320);   // 8192 bf16 (raw)
    __hip_bfloat16* W3b = (__hip_bfloat16*)(ws + 86416);   // 32768 bf16 (sign-folded)
    unsigned* W1p = (unsigned*)(ws + 102800);              // 128 uint
    __hip_bfloat16* W2s = (__hip_bfloat16*)(ws + 102928);  // 8192 bf16 (s2-scaled)
    if (ws_size < (size_t)107024 * 4) return;

    hipMemsetAsync(d_ws, 0, (size_t)65936 * 4, stream);   // mom..maxk

    k_setup<<<1184, 256, 0, stream>>>(pcd, mom, W2, W3, g3, W2b, W3b);
    k_fin1<<<1, 64, 0, stream>>>(mom, W1, b1, g1, be1, W1p);
    k_pass1<<<512, 256, 0, stream>>>(pcd, W1p, W2b, st2s, st2q);
    k_fin2<<<1, 128, 0, stream>>>(st2s, st2q, W2, g2, be2, t2, W2s);
    k_pass2<<<2048, 256, 0, stream>>>(pcd, W1p, W2s, t2, W3b,
                                      st3s, st3q, maxk);
    k_head<<<64, 128, 0, stream>>>(st3s, st3q, g3, be3, maxk,
                                   Wfc, bfc, Wc1, bc1, Wc2, bc2,
                                   Wp1, bp1, Wp2, bp2, (float*)d_out);
}

// Round 14
// 267.561 us; speedup vs baseline: 1.6087x; 1.1670x over previous
//
#include <hip/hip_runtime.h>
#include <hip/hip_bf16.h>

#define NPTS 524288   // 64 * 8192
#define NBATCH 64
#define NSAMP 131072  // 4x-subsampled BN2/BN3 stats denominator

typedef __attribute__((ext_vector_type(8))) short bf16x8;
typedef __attribute__((ext_vector_type(4))) float f32x4;
typedef const float* __restrict__ fp;

__device__ __forceinline__ __hip_bfloat16 f2b(float v) { return __float2bfloat16(v); }
__device__ __forceinline__ unsigned bfbits(float v) {
    union { __hip_bfloat16 h; unsigned short s; } u; u.h = f2b(v); return (unsigned)u.s;
}
__device__ __forceinline__ unsigned pk2(float a, float b) {
    return bfbits(a) | (bfbits(b) << 16);
}
__device__ __forceinline__ float lo2f(unsigned u) { return __uint_as_float(u << 16); }
__device__ __forceinline__ float hi2f(unsigned u) { return __uint_as_float(u & 0xffff0000u); }

__device__ __forceinline__ unsigned fkey(float f) {
    unsigned u = __float_as_uint(f);
    return u ^ ((u & 0x80000000u) ? 0xFFFFFFFFu : 0x80000000u);
}
__device__ __forceinline__ float funkey(unsigned k) {
    unsigned u = (k & 0x80000000u) ? (k ^ 0x80000000u) : ~k;
    return __uint_as_float(u);
}

union U8 { bf16x8 v; __hip_bfloat16 e[8]; unsigned u[4]; };

static __device__ __forceinline__ f32x4 mfma16(bf16x8 a, bf16x8 b, f32x4 c) {
    return __builtin_amdgcn_mfma_f32_16x16x32_bf16(a, b, c, 0, 0, 0);
}

// ---------------- K1: fused W-convert (blocks >=1024) + pcd moments ---------
// W3b is SIGN-FOLDED: W3b[ch][k] = sign(g3[ch]) * W3[ch][k] -> max-only pool.
__launch_bounds__(256)
__global__ void k_setup(fp pcd, float* __restrict__ mom,
                        fp W2, fp W3, fp g3,
                        __hip_bfloat16* __restrict__ W2b,
                        __hip_bfloat16* __restrict__ W3b)
{
    if (blockIdx.x >= 1024) {   // prep branch: 160 blocks cover 8192+32768
        const int i = (blockIdx.x - 1024) * 256 + threadIdx.x;
        if (i < 8192) W2b[i] = f2b(W2[i]);
        const int j = i - 8192;
        if (j >= 0 && j < 32768) {
            const float s = (g3[j >> 7] < 0.f) ? -1.f : 1.f;
            W3b[j] = f2b(s * W3[j]);
        }
        return;
    }
    float s[9];
#pragma unroll
    for (int i = 0; i < 9; ++i) s[i] = 0.f;
    for (int p = blockIdx.x * 256 + threadIdx.x; p < NPTS; p += 262144) {
        const float x = pcd[3*p+0], y = pcd[3*p+1], z = pcd[3*p+2];
        s[0] += x; s[1] += y; s[2] += z;
        s[3] = fmaf(x, x, s[3]); s[4] = fmaf(x, y, s[4]); s[5] = fmaf(x, z, s[5]);
        s[6] = fmaf(y, y, s[6]); s[7] = fmaf(y, z, s[7]); s[8] = fmaf(z, z, s[8]);
    }
#pragma unroll
    for (int off = 1; off < 64; off <<= 1) {
#pragma unroll
        for (int i = 0; i < 9; ++i) s[i] += __shfl_xor(s[i], off);
    }
    __shared__ float red[4][9];
    const int lane = threadIdx.x & 63, wv = threadIdx.x >> 6;
    if (lane == 0) {
#pragma unroll
        for (int i = 0; i < 9; ++i) red[wv][i] = s[i];
    }
    __syncthreads();
    if (threadIdx.x < 9) {
        const int i = threadIdx.x;
        atomicAdd(&mom[i], red[0][i] + red[1][i] + red[2][i] + red[3][i]);
    }
}

// ---------------- K2: analytic BN1 folded straight into W1 ------------------
__global__ void k_fin1(const float* __restrict__ mom, fp W1, fp b1, fp g1, fp be1,
                       unsigned* __restrict__ W1p)
{
    const int c = threadIdx.x;  // 64 threads
    const float inv = 1.f / (float)NPTS;
    const float m0 = mom[0]*inv, m1 = mom[1]*inv, m2 = mom[2]*inv;
    const float c00 = mom[3]*inv - m0*m0, c01 = mom[4]*inv - m0*m1, c02 = mom[5]*inv - m0*m2;
    const float c11 = mom[6]*inv - m1*m1, c12 = mom[7]*inv - m1*m2, c22 = mom[8]*inv - m2*m2;
    const float w0 = W1[c*3+0], w1 = W1[c*3+1], w2 = W1[c*3+2];
    const float mu = w0*m0 + w1*m1 + w2*m2 + b1[c];
    float var = w0*w0*c00 + w1*w1*c11 + w2*w2*c22 + 2.f*(w0*w1*c01 + w0*w2*c02 + w1*w2*c12);
    var = fmaxf(var, 0.f);
    const float sc = g1[c] * rsqrtf(var + 1e-5f);
    const float sh = be1[c] - mu*sc;
    W1p[c*2+0] = pk2(w0*sc, w1*sc);
    W1p[c*2+1] = pk2(w2*sc, b1[c]*sc + sh);
}

// Per-lane VALU L1 -> L2 A-fragment in place; pairwise pack (2 live temps).
#define L1_DIRECT(a2f, px, py, pz)                                              \
    {                                                                           \
        _Pragma("unroll")                                                       \
        for (int ks = 0; ks < 2; ++ks) {                                        \
            _Pragma("unroll")                                                   \
            for (int t2 = 0; t2 < 4; ++t2) {                                    \
                const int t0 = ks*8 + 2*t2;                                     \
                float v0 = fmaf(px, lo2f(wA[t0]), hi2f(wB[t0]));                \
                v0 = fmaf(py, hi2f(wA[t0]), v0);                                \
                v0 = fmaf(pz, lo2f(wB[t0]), v0);                                \
                float v1 = fmaf(px, lo2f(wA[t0+1]), hi2f(wB[t0+1]));            \
                v1 = fmaf(py, hi2f(wA[t0+1]), v1);                              \
                v1 = fmaf(pz, lo2f(wB[t0+1]), v1);                              \
                a2f[ks].u[t2] = pk2(fmaxf(v0, 0.f), fmaxf(v1, 0.f));            \
            }                                                                   \
        }                                                                       \
    }

#define LOAD_W1()                                                               \
    unsigned wA[16], wB[16];                                                    \
    _Pragma("unroll")                                                           \
    for (int t = 0; t < 16; ++t) {                                              \
        const int ch = (t >> 3)*32 + q*8 + (t & 7);                             \
        wA[t] = W1p[ch*2]; wB[t] = W1p[ch*2+1];                                 \
    }

// ---------------- Pass 1: L1 + L2, y2 raw stats on a 1/4 SUBSAMPLE ----------
__launch_bounds__(256, 3)
__global__ void k_pass1(fp pcd, const unsigned* __restrict__ W1p,
                        const __hip_bfloat16* __restrict__ W2b,
                        float* __restrict__ st2s, float* __restrict__ st2q)
{
    __shared__ float red[1024];
    const int tid = threadIdx.x, wv = tid >> 6, lane = tid & 63;
    const int m = lane & 15, q = lane >> 4;
    const int batch = blockIdx.x >> 3, sub = blockIdx.x & 7;

    LOAD_W1()
    bf16x8 wb2[8][2];
#pragma unroll
    for (int nt = 0; nt < 8; ++nt) {
#pragma unroll
        for (int kk = 0; kk < 2; ++kk)
            wb2[nt][kk] = *(const bf16x8*)(W2b + (nt*16+m)*64 + kk*32 + q*8);
    }

    float s_acc[8], q_acc[8];
#pragma unroll
    for (int nt = 0; nt < 8; ++nt) { s_acc[nt] = 0.f; q_acc[nt] = 0.f; }

#pragma unroll
    for (int it = 0; it < 4; ++it) {
        const int p0 = batch*8192 + sub*1024 + it*256 + wv*16;   // strided sample
        const float* pp = pcd + (size_t)(p0 + m) * 3;
        const float px = pp[0], py = pp[1], pz = pp[2];
        U8 a2f[2];
        L1_DIRECT(a2f, px, py, pz)
#pragma unroll
        for (int nt = 0; nt < 8; ++nt) {
            f32x4 c = mfma16(a2f[0].v, wb2[nt][0], (f32x4){0.f,0.f,0.f,0.f});
            c = mfma16(a2f[1].v, wb2[nt][1], c);
            s_acc[nt] += (c[0] + c[1]) + (c[2] + c[3]);
            q_acc[nt] = fmaf(c[0],c[0], fmaf(c[1],c[1], fmaf(c[2],c[2], fmaf(c[3],c[3], q_acc[nt]))));
        }
    }
#pragma unroll
    for (int nt = 0; nt < 8; ++nt) {
        s_acc[nt] += __shfl_xor(s_acc[nt], 16); q_acc[nt] += __shfl_xor(q_acc[nt], 16);
        s_acc[nt] += __shfl_xor(s_acc[nt], 32); q_acc[nt] += __shfl_xor(q_acc[nt], 32);
    }
    if (q == 0) {
#pragma unroll
        for (int nt = 0; nt < 8; ++nt) {
            red[wv*128 + nt*16 + m] = s_acc[nt];
            red[512 + wv*128 + nt*16 + m] = q_acc[nt];
        }
    }
    __syncthreads();
    if (tid < 128) {
        float s = 0.f, ss = 0.f;
#pragma unroll
        for (int w4 = 0; w4 < 4; ++w4) { s += red[w4*128 + tid]; ss += red[512 + w4*128 + tid]; }
        const int slot = blockIdx.x & 63;
        atomicAdd(&st2s[slot*128 + tid], s);
        atomicAdd(&st2q[slot*128 + tid], ss);
    }
}

// ---------------- K4: finalize BN2 + fold s2 into W2 (scaled copy) ----------
__global__ void k_fin2(const float* __restrict__ sum, const float* __restrict__ sq,
                       fp W2, fp g, fp be,
                       float* __restrict__ tOut, __hip_bfloat16* __restrict__ W2s)
{
    const int ch = threadIdx.x;  // 128
    float s = 0.f, ss = 0.f;
    for (int slot = 0; slot < 64; ++slot) { s += sum[slot*128 + ch]; ss += sq[slot*128 + ch]; }
    const float inv = 1.f / (float)NSAMP;
    const float mu = s * inv;
    const float var = fmaxf(ss * inv - mu*mu, 0.f);
    const float sc = g[ch] * rsqrtf(var + 1e-5f);
    tOut[ch] = be[ch] - mu*sc;
    for (int k = 0; k < 64; ++k) W2s[ch*64 + k] = f2b(sc * W2[ch*64 + k]);
}

// ---------------- Pass 2: round-11 structure (measured optimum) -------------
__launch_bounds__(256, 2)
__global__ void k_pass2(fp pcd, const unsigned* __restrict__ W1p,
                        const __hip_bfloat16* __restrict__ W2s,
                        const float* __restrict__ t2,
                        const __hip_bfloat16* __restrict__ W3b,
                        float* __restrict__ st3s, float* __restrict__ st3q,
                        unsigned* __restrict__ maxk)
{
    __shared__ alignas(16) __hip_bfloat16 x2s[256*136];   // 69.6 KB, stride 136
    const int tid = threadIdx.x, wv = tid >> 6, lane = tid & 63;
    const int m = lane & 15, q = lane >> 4;
    const int batch = blockIdx.x >> 5, sub = blockIdx.x & 31;

    LOAD_W1()
    bf16x8 wb2[8][2];
#pragma unroll
    for (int nt = 0; nt < 8; ++nt) {
#pragma unroll
        for (int kk = 0; kk < 2; ++kk)
            wb2[nt][kk] = *(const bf16x8*)(W2s + (nt*16+m)*64 + kk*32 + q*8);
    }
    float t2v[8];
#pragma unroll
    for (int nt = 0; nt < 8; ++nt) t2v[nt] = t2[nt*16+m];

    bf16x8 wb3[4][4];
#pragma unroll
    for (int nt = 0; nt < 4; ++nt) {
        const int ch3 = wv*64 + nt*16 + m;
#pragma unroll
        for (int ks = 0; ks < 4; ++ks)
            wb3[nt][ks] = *(const bf16x8*)(W3b + ch3*128 + ks*32 + q*8);
    }

    // ---- phase A: 4 independent front-end iterations, no barriers ----
#pragma unroll
    for (int it = 0; it < 4; ++it) {
        const int p0 = batch*8192 + sub*256 + it*64 + wv*16;
        const float* pp = pcd + (size_t)(p0 + m) * 3;
        const float px = pp[0], py = pp[1], pz = pp[2];
        U8 a2f[2];
        L1_DIRECT(a2f, px, py, pz)
#pragma unroll
        for (int nt = 0; nt < 8; ++nt) {
            f32x4 c = mfma16(a2f[0].v, wb2[nt][0], (f32x4){0.f,0.f,0.f,0.f});
            c = mfma16(a2f[1].v, wb2[nt][1], c);
#pragma unroll
            for (int r = 0; r < 4; ++r) {
                const float v = fmaxf(c[r] + t2v[nt], 0.f);   // s2 folded into W2
                const unsigned own = bfbits(v);
                const unsigned oth = (unsigned)__shfl_xor((int)own, 1);
                if ((m & 1) == 0) {
                    const int row = it*64 + wv*16 + q*4 + r;
                    *(unsigned*)&x2s[row*136 + nt*16 + m] = own | (oth << 16);
                }
            }
        }
    }
    __syncthreads();   // the ONLY barrier: all 256 x2 rows complete

    // ---- phase B: L3 (sign-folded) over 256 points x 64 channels/wave ----
    float s3[4], q3[4], mx3[4];
#pragma unroll
    for (int nt = 0; nt < 4; ++nt) { s3[nt]=0.f; q3[nt]=0.f; mx3[nt]=-3.4e38f; }

    for (int ms = 0; ms < 16; ++ms) {
        const int rowM = (ms*16 + m) * 136;
        bf16x8 a3[4];
#pragma unroll
        for (int ks = 0; ks < 4; ++ks)
            a3[ks] = *(const bf16x8*)&x2s[rowM + ks*32 + q*8];
        const bool dostat = (ms < 4);   // 1/4 stat subsample; max sees all
#pragma unroll
        for (int nt = 0; nt < 4; ++nt) {
            f32x4 c = mfma16(a3[0], wb3[nt][0], (f32x4){0.f,0.f,0.f,0.f});
            c = mfma16(a3[1], wb3[nt][1], c);
            c = mfma16(a3[2], wb3[nt][2], c);
            c = mfma16(a3[3], wb3[nt][3], c);
            mx3[nt] = fmaxf(fmaxf(c[0], c[1]), fmaxf(fmaxf(c[2], c[3]), mx3[nt]));
            if (dostat) {
                s3[nt] += (c[0] + c[1]) + (c[2] + c[3]);
                q3[nt] = fmaf(c[0],c[0], fmaf(c[1],c[1], fmaf(c[2],c[2], fmaf(c[3],c[3], q3[nt]))));
            }
        }
    }
#pragma unroll
    for (int nt = 0; nt < 4; ++nt) {
        s3[nt] += __shfl_xor(s3[nt], 16);  q3[nt] += __shfl_xor(q3[nt], 16);
        mx3[nt] = fmaxf(mx3[nt], __shfl_xor(mx3[nt], 16));
        s3[nt] += __shfl_xor(s3[nt], 32);  q3[nt] += __shfl_xor(q3[nt], 32);
        mx3[nt] = fmaxf(mx3[nt], __shfl_xor(mx3[nt], 32));
    }
    if (q == 0) {
        const int slot = blockIdx.x & 63;
#pragma unroll
        for (int nt = 0; nt < 4; ++nt) {
            const int ch3 = wv*64 + nt*16 + m;
            atomicAdd(&st3s[slot*256 + ch3], s3[nt]);
            atomicAdd(&st3q[slot*256 + ch3], q3[nt]);
            atomicMax(&maxk[batch*256 + ch3], fkey(mx3[nt]));
        }
    }
}

// ---------------- K6: finalize BN3 constants (once, not per-batch) ----------
// A[ch] = |g3|*rsqrt(var'+eps); B[ch] = be3 - A*mu'  ->  pf = relu(A*mx + B).
__global__ void k_fin3(const float* __restrict__ sum, const float* __restrict__ sq,
                       fp g3, fp be3, float* __restrict__ A, float* __restrict__ B)
{
    const int ch = threadIdx.x;  // 256
    float s = 0.f, ss = 0.f;
    for (int slot = 0; slot < 64; ++slot) { s += sum[slot*256 + ch]; ss += sq[slot*256 + ch]; }
    const float inv = 1.f / (float)NSAMP;
    const float mu = s * inv;
    const float var = fmaxf(ss * inv - mu*mu, 0.f);
    const float a = fabsf(g3[ch]) * rsqrtf(var + 1e-5f);
    A[ch] = a;
    B[ch] = be3[ch] - a*mu;
}

// ---------------- K8: heads + QP (1 block / batch) --------------------------
__launch_bounds__(128)
__global__ void k_head(const float* __restrict__ A, const float* __restrict__ B,
                       const unsigned* __restrict__ maxk,
                       fp Wfc, fp bfc, fp Wc1, fp bc1, fp Wc2, fp bc2,
                       fp Wp1, fp bp1, fp Wp2, fp bp2,
                       float* __restrict__ out)
{
    __shared__ float pf[256], ft[128], hcs[128], hps[64], ocs[48], nrm[36], hS[12], pp[8];
    const int bb = blockIdx.x, tid = threadIdx.x;
#pragma unroll
    for (int h = 0; h < 2; ++h) {
        const int ch = tid + h*128;
        pf[ch] = fmaxf(fmaf(A[ch], funkey(maxk[bb*256 + ch]), B[ch]), 0.f);
    }
    __syncthreads();
    {
        float a = bfc[tid];
        const float* wr = Wfc + tid*256;
        for (int k = 0; k < 256; ++k) a = fmaf(pf[k], wr[k], a);
        ft[tid] = a;
    }
    __syncthreads();
    {
        float a = bc1[tid];
        const float* wr = Wc1 + tid*128;
        for (int k = 0; k < 128; ++k) a = fmaf(ft[k], wr[k], a);
        hcs[tid] = fmaxf(a, 0.f);
    }
    if (tid < 64) {
        float a = bp1[tid];
        const float* wr = Wp1 + tid*128;
        for (int k = 0; k < 128; ++k) a = fmaf(ft[k], wr[k], a);
        hps[tid] = fmaxf(a, 0.f);
    }
    __syncthreads();
    if (tid < 48) {
        float a = bc2[tid];
        const float* wr = Wc2 + tid*128;
        for (int k = 0; k < 128; ++k) a = fmaf(hcs[k], wr[k], a);
        ocs[tid] = a;
    }
    if (tid < 7) {
        float a = bp2[tid];
        const float* wr = Wp2 + tid*64;
        for (int k = 0; k < 64; ++k) a = fmaf(hps[k], wr[k], a);
        const float sc = (tid < 3) ? 0.1f : ((tid < 6) ? 1.57f : 0.05f);
        pp[tid] = tanhf(a) * sc;
    }
    __syncthreads();
    if (tid < 12) {
        float nx = ocs[tid*4+0], ny = ocs[tid*4+1], nz = ocs[tid*4+2];
        const float nn = fmaxf(sqrtf(nx*nx + ny*ny + nz*nz), 1e-12f);
        const float inv = 1.f / nn;
        nx *= inv; ny *= inv; nz *= inv;
        nrm[tid*3+0] = nx; nrm[tid*3+1] = ny; nrm[tid*3+2] = nz;
        const float xx = ocs[tid*4+3];
        hS[tid] = ((xx > 20.f) ? xx : log1pf(expf(xx))) + 0.005f;
    }
    __syncthreads();

    // QP (round-11 form): lanes 0..11 own lam_c; 12 independent broadcasts/iter.
    const int lane = tid & 63;
    const int c = (lane < 12) ? lane : 11;
    const float n0 = nrm[c*3+0], n1 = nrm[c*3+1], n2 = nrm[c*3+2];
    float Mrow[12];
    float trace = 0.f;
#pragma unroll
    for (int d = 0; d < 12; ++d) {
        const float d0 = nrm[d*3+0], d1 = nrm[d*3+1], d2 = nrm[d*3+2];
        Mrow[d] = n0*d0 + n1*d1 + n2*d2 + ((d == lane) ? 5e-4f : 0.f);
        trace += d0*d0 + d1*d1 + d2*d2;
    }
    const float alpha = 1.f / (trace + 12.f*5e-4f);
    const float qc = n0*pp[0] + n1*pp[1] + n2*pp[2] - hS[c];
    float lam = 0.f;
    for (int it = 0; it < 500; ++it) {
        const float l0 = __shfl(lam, 0),  l1 = __shfl(lam, 1),  l2 = __shfl(lam, 2);
        const float l3 = __shfl(lam, 3),  l4 = __shfl(lam, 4),  l5 = __shfl(lam, 5);
        const float l6 = __shfl(lam, 6),  l7 = __shfl(lam, 7),  l8 = __shfl(lam, 8);
        const float l9 = __shfl(lam, 9),  l10 = __shfl(lam, 10), l11 = __shfl(lam, 11);
        const float g0 = fmaf(Mrow[0], l0, fmaf(Mrow[3], l3, fmaf(Mrow[6], l6, Mrow[9]*l9)));
        const float g1 = fmaf(Mrow[1], l1, fmaf(Mrow[4], l4, fmaf(Mrow[7], l7, Mrow[10]*l10)));
        const float g2 = fmaf(Mrow[2], l2, fmaf(Mrow[5], l5, fmaf(Mrow[8], l8, Mrow[11]*l11)));
        lam = fmaxf(fmaf(-alpha, g0 + g1 + g2 - qc, lam), 0.f);
    }
    float v0 = (lane < 12) ? n0*lam : 0.f;
    float v1 = (lane < 12) ? n1*lam : 0.f;
    float v2 = (lane < 12) ? n2*lam : 0.f;
#pragma unroll
    for (int off = 1; off <= 8; off <<= 1) {
        v0 += __shfl_xor(v0, off);
        v1 += __shfl_xor(v1, off);
        v2 += __shfl_xor(v2, off);
    }
    if (tid < 7) {
        float z;
        if (tid == 0) z = pp[0] - v0;
        else if (tid == 1) z = pp[1] - v1;
        else if (tid == 2) z = pp[2] - v2;
        else z = pp[tid];
        out[bb*7 + tid] = z;
    }
    if (tid < 36) out[448 + bb*36 + tid] = nrm[tid];
    if (tid < 12) out[2752 + bb*12 + tid] = hS[tid];
    if (tid < 7)  out[3520 + bb*7 + tid] = pp[tid];
}

// ---------------- host ------------------------------------------------------
extern "C" void kernel_launch(void* const* d_in, const int* in_sizes, int n_in,
                              void* d_out, int out_size, void* d_ws, size_t ws_size,
                              hipStream_t stream) {
    fp pcd = (fp)d_in[0];
    fp W1 = (fp)d_in[1],  b1 = (fp)d_in[2],  g1 = (fp)d_in[3],  be1 = (fp)d_in[4];
    fp W2 = (fp)d_in[5],  g2 = (fp)d_in[7],  be2 = (fp)d_in[8];
    fp W3 = (fp)d_in[9],  g3 = (fp)d_in[11], be3 = (fp)d_in[12];
    fp Wfc = (fp)d_in[13], bfc = (fp)d_in[14];
    fp Wc1 = (fp)d_in[15], bc1 = (fp)d_in[16];
    fp Wc2 = (fp)d_in[17], bc2 = (fp)d_in[18];
    fp Wp1 = (fp)d_in[19], bp1 = (fp)d_in[20];
    fp Wp2 = (fp)d_in[21], bp2 = (fp)d_in[22];
    // b2 (d_in[6]) / b3 (d_in[10]) cancel analytically in BN

    float* ws = (float*)d_ws;
    float* mom  = ws + 0;           // 16
    float* t2   = ws + 272;         // 128
    float* st2s = ws + 400;         // 64*128 = 8192
    float* st2q = ws + 8592;        // 8192
    float* st3s = ws + 16784;       // 64*256 = 16384
    float* st3q = ws + 33168;       // 16384
    unsigned* maxk = (unsigned*)(ws + 49552);   // 16384 (0-init = fkey(-inf))
    float* f3A  = ws + 65936;       // 256
    float* f3B  = ws + 66192;       // 256
    __hip_bfloat16* W2b = (__hip_bfloat16*)(ws + 82320);   // 8192 bf16 (raw)
    __hip_bfloat16* W3b = (__hip_bfloat16*)(ws + 86416);   // 32768 bf16 (sign-folded)
    unsigned* W1p = (unsigned*)(ws + 102800);              // 128 uint
    __hip_bfloat16* W2s = (__hip_bfloat16*)(ws + 102928);  // 8192 bf16 (s2-scaled)
    if (ws_size < (size_t)107024 * 4) return;

    hipMemsetAsync(d_ws, 0, (size_t)65936 * 4, stream);   // mom..maxk

    k_setup<<<1184, 256, 0, stream>>>(pcd, mom, W2, W3, g3, W2b, W3b);
    k_fin1<<<1, 64, 0, stream>>>(mom, W1, b1, g1, be1, W1p);
    k_pass1<<<512, 256, 0, stream>>>(pcd, W1p, W2b, st2s, st2q);
    k_fin2<<<1, 128, 0, stream>>>(st2s, st2q, W2, g2, be2, t2, W2s);
    k_pass2<<<2048, 256, 0, stream>>>(pcd, W1p, W2s, t2, W3b,
                                      st3s, st3q, maxk);
    k_fin3<<<1, 256, 0, stream>>>(st3s, st3q, g3, be3, f3A, f3B);
    k_head<<<64, 128, 0, stream>>>(f3A, f3B, maxk,
                                   Wfc, bfc, Wc1, bc1, Wc2, bc2,
                                   Wp1, bp1, Wp2, bp2, (float*)d_out);
}